// Round 7
// baseline (448.835 us; speedup 1.0000x reference)
//
#include <hip/hip_runtime.h>
#include <hip/hip_cooperative_groups.h>
#include <math.h>

namespace cg = cooperative_groups;

#define Nn 1023

typedef __attribute__((ext_vector_type(8))) short short8;
typedef __attribute__((ext_vector_type(4))) float f32x4;

#define AS1(p) ((const __attribute__((address_space(1))) void*)(p))
#define AS3(p) ((__attribute__((address_space(3))) void*)(p))

__device__ __forceinline__ float sigf(float x) { return 1.0f / (1.0f + __expf(-x)); }
__device__ __forceinline__ float tanhfast(float x) {
    float e = __expf(2.0f * x);
    return 1.0f - 2.0f / (e + 1.0f);
}
__device__ __forceinline__ unsigned short f2bf(float x) {
    unsigned u = __float_as_uint(x);
    return (unsigned short)((u + 0x7fffu + ((u >> 16) & 1u)) >> 16);
}
__device__ __forceinline__ float bf2f(unsigned short b) {
    return __uint_as_float(((unsigned)b) << 16);
}

// ===========================================================================
// P1: fused independent prep. Blocks:
//   [0,1024)    pack_whT  : WhT[P][k2] bf16, P=jhi*64+q*16+jlo, row=q*1024+j
//   [1024,1088) transpose W1 -> W1t
//   [1088,1216) prep_nodes: tyv / alphaf / W2t
//   [1216,1472) e32: E32b[ty][P] = emb[ty]·W_ih[row(P)] + b_ih + b_hh; w511f
//   [1472,1505) zero rowidx (8448) + cnt
// ===========================================================================
__global__ __launch_bounds__(256) void prep_all(
    const float* __restrict__ W_hh, unsigned short* __restrict__ WhT,
    const float* __restrict__ W1, float* __restrict__ W1t,
    const int* __restrict__ node_types, const float* __restrict__ node_args,
    const float* __restrict__ emb, const float* __restrict__ W2,
    float* __restrict__ W2t, int* __restrict__ tyv, float* __restrict__ alphaf,
    const float* __restrict__ W_ih, const float* __restrict__ b_ih,
    const float* __restrict__ b_hh, float* __restrict__ E32b,
    float* __restrict__ w511f, int* __restrict__ rowidx, int* __restrict__ cnt) {
    int bid = blockIdx.x, t = threadIdx.x;
    if (bid < 1024) {
        int idx = bid * 256 + t;
        int P = idx >> 7;
        int k0 = (idx & 127) * 8;
        int row = ((P >> 4) & 3) * 1024 + (P >> 6) * 16 + (P & 15);
        const float* src = W_hh + (size_t)row * 1024 + k0;
        float4 v0 = *(const float4*)src;
        float4 v1 = *(const float4*)(src + 4);
        short8 o;
        o[0] = (short)f2bf(v0.x); o[1] = (short)f2bf(v0.y);
        o[2] = (short)f2bf(v0.z); o[3] = (short)f2bf(v0.w);
        o[4] = (short)f2bf(v1.x); o[5] = (short)f2bf(v1.y);
        o[6] = (short)f2bf(v1.z); o[7] = (short)f2bf(v1.w);
        *(short8*)(WhT + (size_t)P * 1024 + k0) = o;
    } else if (bid < 1088) {
        __shared__ float tile[64][65];
        int idx2 = bid - 1024;
        int jb = (idx2 & 7) * 64, kb = (idx2 >> 3) * 64;
        #pragma unroll
        for (int i = 0; i < 16; ++i) {
            int idx = t + i * 256;
            int lj = idx >> 6, lk = idx & 63;
            tile[lj][lk] = W1[(jb + lj) * 512 + kb + lk];
        }
        __syncthreads();
        #pragma unroll
        for (int i = 0; i < 16; ++i) {
            int idx = t + i * 256;
            int lk = idx >> 6, lj = idx & 63;
            W1t[(kb + lk) * 512 + jb + lj] = tile[lj][lk];
        }
    } else if (bid < 1216) {
        int gid = (bid - 1088) * 256 + t;
        if (gid < 32704) {
            int node = gid >> 6, b = gid & 63;
            int ty = node_types[b * Nn + node];
            tyv[gid] = ty;
            alphaf[gid] = (ty <= 1) ? (node_args[b * Nn + node] - emb[ty * 512 + 511]) : 0.f;
        }
        if (gid < 8192) {
            int k = gid >> 4, op = gid & 15;
            W2t[gid] = W2[op * 512 + k];
        }
    } else if (bid < 1472) {
        int o = (bid - 1216) * 256 + t;
        int ty = o >> 11, P = o & 2047;
        int row = ((P >> 4) & 3) * 1024 + (P >> 6) * 16 + (P & 15);
        const float* er = emb + (size_t)ty * 512;
        const float* wr = W_ih + (size_t)row * 512;
        float s = b_ih[row] + b_hh[row];
        for (int k = 0; k < 512; k += 4) {
            float4 e4 = *(const float4*)(er + k);
            float4 w4 = *(const float4*)(wr + k);
            s = fmaf(e4.x, w4.x, fmaf(e4.y, w4.y, fmaf(e4.z, w4.z, fmaf(e4.w, w4.w, s))));
        }
        E32b[o] = s;
        if (ty == 0) w511f[P] = wr[511];
    } else {
        int z = (bid - 1472) * 256 + t;
        if (z < 8448) rowidx[z] = 0;
        if (bid == 1472 && t == 0) *cnt = 0;
    }
}

// ===========================================================================
// P2: Hleaf (bf16) + Hleaf_f (fp32) + Cleaf: leaf cell for alpha=0.
// ===========================================================================
__global__ __launch_bounds__(256) void leaf_tables(
    const float* __restrict__ E32b,
    unsigned short* __restrict__ Hleaf, float* __restrict__ Hleaf_f,
    float* __restrict__ Cleaf) {
    int o = blockIdx.x * 256 + threadIdx.x;   // 64 blocks
    int ty = o >> 9, j = o & 511;
    int Pb = (j >> 4) * 64 + (j & 15);
    const float* Er = E32b + (size_t)ty * 2048;
    float ig = Er[Pb], gg = Er[Pb + 32], og = Er[Pb + 48];
    float cn = sigf(ig) * tanhfast(gg);
    float hn = sigf(og) * tanhfast(cn);
    Hleaf[o] = f2bf(hn);
    Hleaf_f[o] = hn;
    Cleaf[o] = cn;
}

// ===========================================================================
// P3: fused. Blocks:
//   [0,4096)    leaf_int: Hside/Cside for int leaves (ty<=1)
//   [4096,4608) glgr: GL/GR tables (needs Hleaf_f)
//   [4608,4640) flag: append d=7 rows with int-leaf child to rowidx
// ===========================================================================
__global__ __launch_bounds__(256) void leaf_side(
    const float* __restrict__ E32b, const float* __restrict__ w511f,
    const int* __restrict__ tyv, const float* __restrict__ alphaf,
    unsigned short* __restrict__ Hside, float* __restrict__ Cside,
    const float* __restrict__ W_hh, const float* __restrict__ Hleaf_f,
    float* __restrict__ GLt, float* __restrict__ GRt,
    int* __restrict__ rowidx, int* __restrict__ cnt) {
    int bid = blockIdx.x, t = threadIdx.x;
    if (bid < 4096) {
        int r = bid * 4 + (t >> 6);
        int gn = 16320 + r;
        int ty = tyv[gn];
        if (ty > 1) return;
        float al = alphaf[gn];
        int l = r >> 6, b = r & 63;
        int jc = (t & 63) * 8;
        const float* Er = E32b + (size_t)ty * 2048;
        short8 hv;
        float cv[8];
        #pragma unroll
        for (int jj = 0; jj < 8; ++jj) {
            int j = jc + jj;
            int Pb = (j >> 4) * 64 + (j & 15);
            float ig = Er[Pb]      + al * w511f[Pb];
            float gg = Er[Pb + 32] + al * w511f[Pb + 32];
            float og = Er[Pb + 48] + al * w511f[Pb + 48];
            float cn = sigf(ig) * tanhfast(gg);
            float hn = sigf(og) * tanhfast(cn);
            hv[jj] = (short)f2bf(hn);
            cv[jj] = cn;
        }
        *(short8*)(Hside + (size_t)r * 512 + jc) = hv;
        if ((l & 1) == 0) {
            size_t cr = ((size_t)((l >> 1) * 64 + b)) * 512 + jc;
            float4 c0 = {cv[0], cv[1], cv[2], cv[3]};
            float4 c1 = {cv[4], cv[5], cv[6], cv[7]};
            *(float4*)(Cside + cr) = c0;
            *(float4*)(Cside + cr + 4) = c1;
        }
    } else if (bid < 4608) {
        int gid = (bid - 4096) * 256 + t;   // [0,131072)
        int side = gid >> 16, ty = (gid >> 11) & 31, P = gid & 2047;
        int row = ((P >> 4) & 3) * 1024 + (P >> 6) * 16 + (P & 15);
        const float* wr = W_hh + (size_t)row * 1024 + side * 512;
        const float* hr = Hleaf_f + (size_t)ty * 512;
        float s = 0.f;
        for (int k = 0; k < 512; k += 4) {
            float4 w4 = *(const float4*)(wr + k);
            float4 h4 = *(const float4*)(hr + k);
            s = fmaf(w4.x, h4.x, fmaf(w4.y, h4.y, fmaf(w4.z, h4.z, fmaf(w4.w, h4.w, s))));
        }
        if (side == 0) GLt[ty * 2048 + P] = s;
        else           GRt[ty * 2048 + P] = s;
    } else {
        int r = (bid - 4608) * 256 + t;     // [0,8192)
        int lf = (r >> 6) * 128 + (r & 63);
        if (tyv[16320 + lf] <= 1 || tyv[16320 + lf + 64] <= 1) {
            int p = atomicAdd(cnt, 1);
            rowidx[p] = r;
        }
    }
}

__global__ void zero_out(float* __restrict__ outp, int n) {
    int i = blockIdx.x * 256 + threadIdx.x;
    if (i < n) outp[i] = 0.f;
}

// ===========================================================================
// Device body: d=7 table path (all rows; int-child rows overwritten later).
// smem layout (floats): Es[32][129] GLs[32][129] GRs[32][129] Cls[32][33] w5s[128]
// ===========================================================================
__device__ __forceinline__ void d7_table_body(
    char* smemraw,
    const float* __restrict__ E32b, const float* __restrict__ GLt,
    const float* __restrict__ GRt, const float* __restrict__ Cleaf,
    const float* __restrict__ Cside, const float* __restrict__ w511f,
    const int* __restrict__ tyv, const float* __restrict__ alphaf,
    unsigned short* __restrict__ out_h, float* __restrict__ out_c,
    int bx, int by) {
    float* Es  = (float*)smemraw;
    float* GLs = Es + 32 * 129;
    float* GRs = GLs + 32 * 129;
    float* Cls = GRs + 32 * 129;
    float* w5s = Cls + 32 * 33;
    const int t = threadIdx.x;
    const int j0 = by * 32;
    const int r = bx * 256 + t;

    for (int i = t; i < 32 * 128; i += 256) {
        int ty = i >> 7, pp = i & 127;
        int gp = ((j0 >> 4) + (pp >> 6)) * 64 + (pp & 63);
        Es[ty * 129 + pp]  = E32b[ty * 2048 + gp];
        GLs[ty * 129 + pp] = GLt[ty * 2048 + gp];
        GRs[ty * 129 + pp] = GRt[ty * 2048 + gp];
    }
    for (int i = t; i < 32 * 32; i += 256) {
        int ty = i >> 5, jl = i & 31;
        Cls[ty * 33 + jl] = Cleaf[ty * 512 + j0 + jl];
    }
    if (t < 128) w5s[t] = w511f[((j0 >> 4) + (t >> 6)) * 64 + (t & 63)];
    __syncthreads();

    int gn = 8128 + r;
    int tyP = tyv[gn];
    float aP = alphaf[gn];
    int lf = (r >> 6) * 128 + (r & 63);
    int tyL = tyv[16320 + lf];
    int tyR = tyv[16320 + lf + 64];
    bool intL = (tyL <= 1);
    bool evenl = (((r >> 6) & 1) == 0);
    size_t crow = ((size_t)((r >> 7) * 64 + (r & 63))) * 512;

    #pragma unroll
    for (int j8 = 0; j8 < 4; ++j8) {
        short8 hv;
        float cv[8];
        #pragma unroll
        for (int jj = 0; jj < 8; ++jj) {
            int jl = j8 * 8 + jj;
            int ppb = (jl >> 4) * 64 + (jl & 15);
            float ig = Es[tyP * 129 + ppb]      + aP * w5s[ppb]      + GLs[tyL * 129 + ppb]      + GRs[tyR * 129 + ppb];
            float fg = Es[tyP * 129 + ppb + 16] + aP * w5s[ppb + 16] + GLs[tyL * 129 + ppb + 16] + GRs[tyR * 129 + ppb + 16];
            float gg = Es[tyP * 129 + ppb + 32] + aP * w5s[ppb + 32] + GLs[tyL * 129 + ppb + 32] + GRs[tyR * 129 + ppb + 32];
            float og = Es[tyP * 129 + ppb + 48] + aP * w5s[ppb + 48] + GLs[tyL * 129 + ppb + 48] + GRs[tyR * 129 + ppb + 48];
            float cl = intL ? Cside[(size_t)r * 512 + j0 + jl] : Cls[tyL * 33 + jl];
            float cn = sigf(fg) * cl + sigf(ig) * tanhfast(gg);
            float hn = sigf(og) * tanhfast(cn);
            hv[jj] = (short)f2bf(hn);
            cv[jj] = cn;
        }
        *(short8*)(out_h + (size_t)r * 512 + j0 + j8 * 8) = hv;
        if (evenl) {
            float4 c0 = {cv[0], cv[1], cv[2], cv[3]};
            float4 c1 = {cv[4], cv[5], cv[6], cv[7]};
            *(float4*)(out_c + crow + j0 + j8 * 8) = c0;
            *(float4*)(out_c + crow + j0 + j8 * 8 + 4) = c1;
        }
    }
    __syncthreads();   // LDS reused by next phase
}

// ===========================================================================
// Device body: one 128x128 MFMA tile of a level. MODE 0: inner; MODE 1/2:
// leaf-children (MODE 2 row-compacted via rowidx). Single-barrier dbuf K-loop.
// smem: 64 KB (2 x (A 16KB + B 16KB)).
// ===========================================================================
template<int MODE>
__device__ __forceinline__ void mfma_tile(
    char* smemraw,
    const unsigned short* __restrict__ WhT, const float* __restrict__ E32b,
    const float* __restrict__ w511f,
    const int* __restrict__ tyv, const float* __restrict__ alphaf,
    const unsigned short* __restrict__ in_h, const float* __restrict__ in_c,
    const unsigned short* __restrict__ Hleaf, const unsigned short* __restrict__ Hside,
    const float* __restrict__ Cleaf, const float* __restrict__ Cside,
    const int* __restrict__ rowidx,
    unsigned short* __restrict__ out_h, float* __restrict__ out_c,
    int base, int nloc, int bx, int by) {
    unsigned short* AB = (unsigned short*)smemraw;
    const int t = threadIdx.x;
    const int w = t >> 6, lane = t & 63;
    const int wr = w >> 1, wc = w & 1;
    const int lane15 = lane & 15, lg = lane >> 4;
    const int M = nloc * 64;
    const int brow0 = bx * 128;
    const int bcol0 = by * 128;
    const int lanek8 = (lane & 7) * 8;

    const unsigned short* baseL[4];
    const unsigned short* baseR[4];
    const unsigned short* wB[4];
    #pragma unroll
    for (int q = 0; q < 4; ++q) {
        int m = w * 32 + q * 8 + (lane >> 3);
        int r = brow0 + m;
        if (MODE == 2) r = rowidx[r];
        else if (r > M - 1) r = M - 1;
        int lf = (r >> 6) * 128 + (r & 63);
        if (MODE >= 1) {
            int tyL = tyv[16320 + lf];
            int tyR = tyv[16320 + lf + 64];
            baseL[q] = (tyL <= 1) ? (Hside + (size_t)lf * 512)
                                  : (Hleaf + (size_t)tyL * 512);
            baseR[q] = (tyR <= 1) ? (Hside + (size_t)(lf + 64) * 512)
                                  : (Hleaf + (size_t)tyR * 512);
        } else {
            baseL[q] = in_h + (size_t)lf * 512;
            baseR[q] = baseL[q] + 64 * 512;
        }
        int P = bcol0 + w * 32 + q * 8 + (lane >> 3);
        wB[q] = WhT + (size_t)P * 1024;
    }

    auto stage = [&](int kt, int cur) {
        unsigned short* Ad = AB + cur * 16384;
        unsigned short* Bd = Ad + 8192;
        #pragma unroll
        for (int q = 0; q < 4; ++q) {
            const unsigned short* s = (kt < 8) ? (baseL[q] + kt * 64)
                                               : (baseR[q] + (kt - 8) * 64);
            __builtin_amdgcn_global_load_lds(AS1(s + lanek8),
                                             AS3(Ad + w * 2048 + q * 512), 16, 0, 0);
            __builtin_amdgcn_global_load_lds(AS1(wB[q] + kt * 64 + lanek8),
                                             AS3(Bd + w * 2048 + q * 512), 16, 0, 0);
        }
    };

    stage(0, 0);

    f32x4 acc[4][4];
    float w4[4];
    int P4[4];
    int rr[4][4];
    #pragma unroll
    for (int q = 0; q < 4; ++q) {
        P4[q] = bcol0 + wc * 64 + q * 16 + lane15;
        w4[q] = w511f[P4[q]];
    }
    #pragma unroll
    for (int mi = 0; mi < 4; ++mi) {
        #pragma unroll
        for (int reg = 0; reg < 4; ++reg) {
            int r = brow0 + wr * 64 + mi * 16 + lg * 4 + reg;
            if (MODE == 2) r = rowidx[r];
            else if (r > M - 1) r = M - 1;
            rr[mi][reg] = r;
            int gn = base * 64 + r;
            int ty = tyv[gn];
            float al = alphaf[gn];
            const float* Er = E32b + (size_t)ty * 2048;
            #pragma unroll
            for (int q = 0; q < 4; ++q)
                acc[mi][q][reg] = Er[P4[q]] + al * w4[q];
        }
    }

    int cur = 0;
    for (int kt = 0; kt < 16; ++kt) {
        __syncthreads();
        if (kt < 15) stage(kt + 1, cur ^ 1);
        const unsigned short* Ac = AB + cur * 16384;
        const unsigned short* Bc = Ac + 8192;
        #pragma unroll
        for (int ks = 0; ks < 2; ++ks) {
            short8 av[4], bv[4];
            #pragma unroll
            for (int mi = 0; mi < 4; ++mi)
                av[mi] = *(const short8*)(Ac + (wr * 64 + mi * 16 + lane15) * 64 + ks * 32 + lg * 8);
            #pragma unroll
            for (int q = 0; q < 4; ++q)
                bv[q] = *(const short8*)(Bc + (wc * 64 + q * 16 + lane15) * 64 + ks * 32 + lg * 8);
            #pragma unroll
            for (int mi = 0; mi < 4; ++mi)
                #pragma unroll
                for (int q = 0; q < 4; ++q)
                    acc[mi][q] = __builtin_amdgcn_mfma_f32_16x16x32_bf16(av[mi], bv[q], acc[mi][q], 0, 0, 0);
        }
        cur ^= 1;
    }

    const int j = (by * 2 + wc) * 16 + lane15;
    #pragma unroll
    for (int mi = 0; mi < 4; ++mi) {
        #pragma unroll
        for (int reg = 0; reg < 4; ++reg) {
            int r = rr[mi][reg];
            if (r < M) {
                float ig = acc[mi][0][reg];
                float fg = acc[mi][1][reg];
                float gg = acc[mi][2][reg];
                float og = acc[mi][3][reg];
                float cl;
                if (MODE >= 1) {
                    int lf = (r >> 6) * 128 + (r & 63);
                    int tyL = tyv[16320 + lf];
                    cl = (tyL <= 1) ? Cside[(size_t)r * 512 + j]
                                    : Cleaf[(size_t)tyL * 512 + j];
                } else {
                    cl = in_c[(size_t)r * 512 + j];
                }
                float cn = sigf(fg) * cl + sigf(ig) * tanhfast(gg);
                float hn = sigf(og) * tanhfast(cn);
                out_h[(size_t)r * 512 + j] = f2bf(hn);
                if (((r >> 6) & 1) == 0)
                    out_c[((size_t)((r >> 7) * 64 + (r & 63))) * 512 + j] = cn;
            }
        }
    }
}

// ===========================================================================
// Device body: head. smem floats: rh[512] xs[512] part[16*17]
// ===========================================================================
__device__ __forceinline__ void head_body(
    char* smemraw,
    const unsigned short* __restrict__ rootH, const float* __restrict__ W1t,
    const float* __restrict__ b1, const float* __restrict__ W2t,
    const float* __restrict__ b2, const float* __restrict__ vmask,
    float* __restrict__ outp, int b) {
    float* rh = (float*)smemraw;
    float* xs = rh + 512;
    float* part = xs + 512;
    int t = threadIdx.x;
    rh[t] = bf2f(rootH[b * 512 + t]);
    rh[t + 256] = bf2f(rootH[b * 512 + t + 256]);
    __syncthreads();
    #pragma unroll
    for (int jj = 0; jj < 2; ++jj) {
        int jx = t + jj * 256;
        float acc = b1[jx];
        for (int k = 0; k < 512; ++k) acc = fmaf(rh[k], W1t[k * 512 + jx], acc);
        xs[jx] = fmaxf(acc, 0.f);
    }
    __syncthreads();
    int op = t & 15, seg = t >> 4;
    float p = 0.f;
    for (int k = seg * 32; k < seg * 32 + 32; ++k) p = fmaf(xs[k], W2t[k * 16 + op], p);
    part[seg * 17 + op] = p;
    __syncthreads();
    if (t < 16) {
        float s = 0.f;
        #pragma unroll
        for (int g = 0; g < 16; ++g) s += part[g * 17 + t];
        float logit = s + b2[t] + logf(vmask[b * 16 + t]);
        float z = logit * (1.0f / 3.0f);
        float m = z;
        for (int o2 = 8; o2; o2 >>= 1) m = fmaxf(m, __shfl_xor(m, o2, 16));
        float e = __expf(z - m);
        float ssum = e;
        for (int o2 = 8; o2; o2 >>= 1) ssum += __shfl_xor(ssum, o2, 16);
        outp[b * 16 + t] = e / ssum;
    }
}

// ===========================================================================
// Cooperative fused tree: d7 table -> d7 compacted MFMA -> d6..0 -> head.
// Grid 512 blocks x 256 threads, 64 KB dyn LDS, grid.sync between phases.
// ===========================================================================
__global__ __launch_bounds__(256) void tree_main(
    const unsigned short* WhT, const float* E32b, const float* w511f,
    const int* tyv, const float* alphaf,
    const unsigned short* Hleaf, const unsigned short* Hside,
    const float* Cleaf, const float* Cside,
    const float* GLt, const float* GRt,
    const int* rowidx, const int* cnt,
    unsigned short* Xh, float* Xc, unsigned short* Yh, float* Yc,
    const float* W1t, const float* b1, const float* W2t, const float* b2,
    const float* vmask, float* outp) {
    cg::grid_group grid = cg::this_grid();
    extern __shared__ char smem[];
    const int bid = blockIdx.x;

    // phase 0: d=7 table path (exactly 512 tiles)
    d7_table_body(smem, E32b, GLt, GRt, Cleaf, Cside, w511f, tyv, alphaf,
                  Xh, Xc, bid & 31, bid >> 5);
    __threadfence(); grid.sync();

    // phase 1: d=7 compacted MFMA overwrite of int-child rows
    {
        int nc = *cnt;
        int rb = ((nc + 127) & ~127) >> 7;
        int ntiles = rb * 16;
        for (int T = bid; T < ntiles; T += 512)
            mfma_tile<2>(smem, WhT, E32b, w511f, tyv, alphaf, nullptr, nullptr,
                         Hleaf, Hside, Cleaf, Cside, rowidx,
                         Xh, Xc, 127, 128, T % rb, T / rb);
    }
    __threadfence(); grid.sync();

    // phases 2..8: levels d=6..0
    for (int d = 6; d >= 0; --d) {
        int nloc = 1 << d;
        int gx = (nloc >= 2) ? (nloc >> 1) : 1;
        unsigned short* oh = (d & 1) ? Xh : Yh;
        float* oc          = (d & 1) ? Xc : Yc;
        const unsigned short* ih = (d & 1) ? Yh : Xh;
        const float* ic          = (d & 1) ? Yc : Xc;
        int ntiles = gx * 16;
        if (bid < ntiles)
            mfma_tile<0>(smem, WhT, E32b, w511f, tyv, alphaf, ih, ic,
                         nullptr, nullptr, nullptr, nullptr, nullptr,
                         oh, oc, nloc - 1, nloc, bid % gx, bid / gx);
        __threadfence(); grid.sync();
    }

    // phase 9: head (root h in Yh)
    if (bid < 64)
        head_body(smem, Yh, W1t, b1, W2t, b2, vmask, outp, bid);
}

// ===========================================================================
// Fallback wrappers (non-cooperative path)
// ===========================================================================
__global__ __launch_bounds__(256) void d7_table_cell_k(
    const float* __restrict__ E32b, const float* __restrict__ GLt,
    const float* __restrict__ GRt, const float* __restrict__ Cleaf,
    const float* __restrict__ Cside, const float* __restrict__ w511f,
    const int* __restrict__ tyv, const float* __restrict__ alphaf,
    unsigned short* __restrict__ out_h, float* __restrict__ out_c) {
    extern __shared__ char smem[];
    d7_table_body(smem, E32b, GLt, GRt, Cleaf, Cside, w511f, tyv, alphaf,
                  out_h, out_c, blockIdx.x, blockIdx.y);
}

template<int MODE>
__global__ __launch_bounds__(256) void lstm_mfma_k(
    const unsigned short* __restrict__ WhT, const float* __restrict__ E32b,
    const float* __restrict__ w511f,
    const int* __restrict__ tyv, const float* __restrict__ alphaf,
    const unsigned short* __restrict__ in_h, const float* __restrict__ in_c,
    const unsigned short* __restrict__ Hleaf, const unsigned short* __restrict__ Hside,
    const float* __restrict__ Cleaf, const float* __restrict__ Cside,
    const int* __restrict__ rowidx, const int* __restrict__ cnt,
    unsigned short* __restrict__ out_h, float* __restrict__ out_c,
    int base, int nloc) {
    extern __shared__ char smem[];
    if (MODE == 2) {
        int nc = *cnt;
        int padded = (nc + 127) & ~127;
        if ((int)blockIdx.x * 128 >= padded) return;
    }
    mfma_tile<MODE>(smem, WhT, E32b, w511f, tyv, alphaf, in_h, in_c,
                    Hleaf, Hside, Cleaf, Cside, rowidx,
                    out_h, out_c, base, nloc, blockIdx.x, blockIdx.y);
}

__global__ __launch_bounds__(256) void head_k(
    const unsigned short* __restrict__ rootH, const float* __restrict__ W1t,
    const float* __restrict__ b1, const float* __restrict__ W2t,
    const float* __restrict__ b2, const float* __restrict__ vmask,
    float* __restrict__ outp) {
    extern __shared__ char smem[];
    head_body(smem, rootH, W1t, b1, W2t, b2, vmask, outp, blockIdx.x);
}

extern "C" void kernel_launch(void* const* d_in, const int* in_sizes, int n_in,
                              void* d_out, int out_size, void* d_ws, size_t ws_size,
                              hipStream_t stream) {
    const int*   node_types = (const int*)d_in[0];
    const float* node_args  = (const float*)d_in[1];
    const float* vmask      = (const float*)d_in[2];
    const float* emb_table  = (const float*)d_in[3];
    const float* W_ih       = (const float*)d_in[4];
    const float* W_hh       = (const float*)d_in[5];
    const float* b_ih       = (const float*)d_in[6];
    const float* b_hh       = (const float*)d_in[7];
    const float* W1         = (const float*)d_in[8];
    const float* b1         = (const float*)d_in[9];
    const float* W2         = (const float*)d_in[10];
    const float* b2         = (const float*)d_in[11];
    float* out = (float*)d_out;

    char* ws = (char*)d_ws;
    size_t off = 0;
    auto alloc = [&](size_t bytes) { char* p = ws + off; off += (bytes + 255) & ~(size_t)255; return p; };
    unsigned short* WhT  = (unsigned short*)alloc((size_t)2048 * 1024 * 2);
    float* E32b          = (float*)alloc((size_t)32 * 2048 * 4);
    float* w511f         = (float*)alloc(2048 * 4);
    float* W1t           = (float*)alloc((size_t)512 * 512 * 4);
    float* W2t           = (float*)alloc(8192 * 4);
    int*   tyv           = (int*)alloc(32704 * 4);
    float* alphaf        = (float*)alloc(32704 * 4);
    unsigned short* Hleaf= (unsigned short*)alloc((size_t)32 * 512 * 2);
    float* Hleaf_f       = (float*)alloc((size_t)32 * 512 * 4);
    float* Cleaf         = (float*)alloc((size_t)32 * 512 * 4);
    float* GLt           = (float*)alloc((size_t)32 * 2048 * 4);
    float* GRt           = (float*)alloc((size_t)32 * 2048 * 4);
    int*   rowidx        = (int*)alloc(8448 * 4);
    int*   cnt           = (int*)alloc(256);
    unsigned short* Hside= (unsigned short*)alloc((size_t)16384 * 512 * 2);
    float* Cside         = (float*)alloc((size_t)8192 * 512 * 4);
    unsigned short* Xh   = (unsigned short*)alloc((size_t)8192 * 512 * 2);
    unsigned short* Yh   = (unsigned short*)alloc((size_t)4096 * 512 * 2);
    float* Xc            = (float*)alloc((size_t)4096 * 512 * 4);
    float* Yc            = (float*)alloc((size_t)2048 * 512 * 4);

    if (ws_size < off) {
        zero_out<<<(out_size + 255) / 256, 256, 0, stream>>>(out, out_size);
        return;
    }

    prep_all<<<1505, 256, 0, stream>>>(W_hh, WhT, W1, W1t, node_types, node_args,
                                       emb_table, W2, W2t, tyv, alphaf,
                                       W_ih, b_ih, b_hh, E32b, w511f, rowidx, cnt);
    leaf_tables<<<64, 256, 0, stream>>>(E32b, Hleaf, Hleaf_f, Cleaf);
    leaf_side<<<4640, 256, 0, stream>>>(E32b, w511f, tyv, alphaf, Hside, Cside,
                                        W_hh, Hleaf_f, GLt, GRt, rowidx, cnt);

    // cooperative fused tree if occupancy allows 2 blocks/CU (512 blocks)
    bool coop_ok = false;
    {
        int occ = 0;
        hipError_t qe = hipOccupancyMaxActiveBlocksPerMultiprocessor(
            &occ, tree_main, 256, 65536);
        if (qe == hipSuccess && occ >= 2) coop_ok = true;
    }
    if (coop_ok) {
        const unsigned short* cWhT = WhT;  const float* cE32b = E32b;
        const float* cw511 = w511f;        const int* ctyv = tyv;
        const float* calpha = alphaf;      const unsigned short* cHleaf = Hleaf;
        const unsigned short* cHside = Hside; const float* cCleaf = Cleaf;
        const float* cCside = Cside;       const float* cGL = GLt;
        const float* cGR = GRt;            const int* cridx = rowidx;
        const int* ccnt = cnt;             const float* cW1t = W1t;
        const float* cW2t = W2t;
        void* kargs[] = {
            (void*)&cWhT, (void*)&cE32b, (void*)&cw511, (void*)&ctyv, (void*)&calpha,
            (void*)&cHleaf, (void*)&cHside, (void*)&cCleaf, (void*)&cCside,
            (void*)&cGL, (void*)&cGR, (void*)&cridx, (void*)&ccnt,
            (void*)&Xh, (void*)&Xc, (void*)&Yh, (void*)&Yc,
            (void*)&cW1t, (void*)&b1, (void*)&cW2t, (void*)&b2,
            (void*)&vmask, (void*)&out };
        hipError_t le = hipLaunchCooperativeKernel(
            tree_main, dim3(512), dim3(256), kargs, (unsigned)65536, stream);
        if (le != hipSuccess) coop_ok = false;
    }
    if (!coop_ok) {
        d7_table_cell_k<<<dim3(32, 16), 256, 54272, stream>>>(
            E32b, GLt, GRt, Cleaf, Cside, w511f, tyv, alphaf, Xh, Xc);
        lstm_mfma_k<2><<<dim3(64, 16), 256, 65536, stream>>>(
            WhT, E32b, w511f, tyv, alphaf, nullptr, nullptr,
            Hleaf, Hside, Cleaf, Cside, rowidx, cnt, Xh, Xc, 127, 128);
        for (int d = 6; d >= 0; --d) {
            int nloc = 1 << d;
            unsigned short* oh = (d & 1) ? Xh : Yh;
            float* oc          = (d & 1) ? Xc : Yc;
            const unsigned short* ih = (d & 1) ? Yh : Xh;
            const float* ic          = (d & 1) ? Yc : Xc;
            int gx = (nloc >= 2) ? (nloc / 2) : 1;
            lstm_mfma_k<0><<<dim3(gx, 16), 256, 65536, stream>>>(
                WhT, E32b, w511f, tyv, alphaf, ih, ic,
                nullptr, nullptr, nullptr, nullptr,
                nullptr, nullptr, oh, oc, nloc - 1, nloc);
        }
        head_k<<<64, 256, 5184, stream>>>(Yh, W1t, b1, W2t, b2, vmask, out);
    }
}

// Round 8
// 384.720 us; speedup vs baseline: 1.1667x; 1.1667x over previous
//
#include <hip/hip_runtime.h>
#include <hip/hip_cooperative_groups.h>
#include <math.h>

namespace cg = cooperative_groups;

#define Nn 1023

typedef __attribute__((ext_vector_type(8))) short short8;
typedef __attribute__((ext_vector_type(4))) float f32x4;

#define AS1(p) ((const __attribute__((address_space(1))) void*)(p))
#define AS3(p) ((__attribute__((address_space(3))) void*)(p))

__device__ __forceinline__ float sigf(float x) { return 1.0f / (1.0f + __expf(-x)); }
__device__ __forceinline__ float tanhfast(float x) {
    float e = __expf(2.0f * x);
    return 1.0f - 2.0f / (e + 1.0f);
}
__device__ __forceinline__ unsigned short f2bf(float x) {
    unsigned u = __float_as_uint(x);
    return (unsigned short)((u + 0x7fffu + ((u >> 16) & 1u)) >> 16);
}
__device__ __forceinline__ float bf2f(unsigned short b) {
    return __uint_as_float(((unsigned)b) << 16);
}

// ===========================================================================
// prep_all (1505 blocks):
//   [0,1024)    pack WhT[P][k2] bf16 (P = jhi*64+q*16+jlo, row=q*1024+j)
//   [1024,1088) W1 -> W1t
//   [1088,1216) tyv/alphaf/W2t
//   [1216,1472) e32 (fp32, 4 partial accs): E32b[ty][P] + bias; w511f[P]
//   [1472,1505) zero rowidx(8448) + cnt
// ===========================================================================
__global__ __launch_bounds__(256) void prep_all(
    const float* __restrict__ W_hh, unsigned short* __restrict__ WhT,
    const float* __restrict__ W1, float* __restrict__ W1t,
    const int* __restrict__ node_types, const float* __restrict__ node_args,
    const float* __restrict__ emb, const float* __restrict__ W2,
    float* __restrict__ W2t, int* __restrict__ tyv, float* __restrict__ alphaf,
    const float* __restrict__ W_ih, const float* __restrict__ b_ih,
    const float* __restrict__ b_hh, float* __restrict__ E32b,
    float* __restrict__ w511f, int* __restrict__ rowidx, int* __restrict__ cnt) {
    int bid = blockIdx.x, t = threadIdx.x;
    if (bid < 1024) {
        int idx = bid * 256 + t;
        int P = idx >> 7;
        int k0 = (idx & 127) * 8;
        int row = ((P >> 4) & 3) * 1024 + (P >> 6) * 16 + (P & 15);
        const float* src = W_hh + (size_t)row * 1024 + k0;
        float4 v0 = *(const float4*)src;
        float4 v1 = *(const float4*)(src + 4);
        short8 o;
        o[0] = (short)f2bf(v0.x); o[1] = (short)f2bf(v0.y);
        o[2] = (short)f2bf(v0.z); o[3] = (short)f2bf(v0.w);
        o[4] = (short)f2bf(v1.x); o[5] = (short)f2bf(v1.y);
        o[6] = (short)f2bf(v1.z); o[7] = (short)f2bf(v1.w);
        *(short8*)(WhT + (size_t)P * 1024 + k0) = o;
    } else if (bid < 1088) {
        __shared__ float tile[64][65];
        int idx2 = bid - 1024;
        int jb = (idx2 & 7) * 64, kb = (idx2 >> 3) * 64;
        #pragma unroll
        for (int i = 0; i < 16; ++i) {
            int idx = t + i * 256;
            int lj = idx >> 6, lk = idx & 63;
            tile[lj][lk] = W1[(jb + lj) * 512 + kb + lk];
        }
        __syncthreads();
        #pragma unroll
        for (int i = 0; i < 16; ++i) {
            int idx = t + i * 256;
            int lk = idx >> 6, lj = idx & 63;
            W1t[(kb + lk) * 512 + jb + lj] = tile[lj][lk];
        }
    } else if (bid < 1216) {
        int gid = (bid - 1088) * 256 + t;
        if (gid < 32704) {
            int node = gid >> 6, b = gid & 63;
            int ty = node_types[b * Nn + node];
            tyv[gid] = ty;
            alphaf[gid] = (ty <= 1) ? (node_args[b * Nn + node] - emb[ty * 512 + 511]) : 0.f;
        }
        if (gid < 8192) {
            int k = gid >> 4, op = gid & 15;
            W2t[gid] = W2[op * 512 + k];
        }
    } else if (bid < 1472) {
        int o = (bid - 1216) * 256 + t;
        int ty = o >> 11, P = o & 2047;
        int row = ((P >> 4) & 3) * 1024 + (P >> 6) * 16 + (P & 15);
        const float* er = emb + (size_t)ty * 512;
        const float* wr = W_ih + (size_t)row * 512;
        float s0 = b_ih[row] + b_hh[row], s1 = 0.f, s2 = 0.f, s3 = 0.f;
        for (int k = 0; k < 512; k += 16) {
            float4 e0 = *(const float4*)(er + k);
            float4 w0 = *(const float4*)(wr + k);
            float4 e1 = *(const float4*)(er + k + 4);
            float4 w1 = *(const float4*)(wr + k + 4);
            float4 e2 = *(const float4*)(er + k + 8);
            float4 w2 = *(const float4*)(wr + k + 8);
            float4 e3 = *(const float4*)(er + k + 12);
            float4 w3 = *(const float4*)(wr + k + 12);
            s0 = fmaf(e0.x, w0.x, fmaf(e0.y, w0.y, fmaf(e0.z, w0.z, fmaf(e0.w, w0.w, s0))));
            s1 = fmaf(e1.x, w1.x, fmaf(e1.y, w1.y, fmaf(e1.z, w1.z, fmaf(e1.w, w1.w, s1))));
            s2 = fmaf(e2.x, w2.x, fmaf(e2.y, w2.y, fmaf(e2.z, w2.z, fmaf(e2.w, w2.w, s2))));
            s3 = fmaf(e3.x, w3.x, fmaf(e3.y, w3.y, fmaf(e3.z, w3.z, fmaf(e3.w, w3.w, s3))));
        }
        E32b[o] = (s0 + s1) + (s2 + s3);
        if (ty == 0) w511f[P] = wr[511];
    } else {
        int z = (bid - 1472) * 256 + t;
        if (z < 8448) rowidx[z] = 0;
        if (bid == 1472 && t == 0) *cnt = 0;
    }
}

__global__ void zero_out(float* __restrict__ outp, int n) {
    int i = blockIdx.x * 256 + threadIdx.x;
    if (i < n) outp[i] = 0.f;
}

// ===========================================================================
// ph0 body: leaf tables + A64 build (bid<64), leaf_int (all blocks, strided),
// flag d=7 int-child rows (bid in [64,96)). No early returns (coop-safe).
// ===========================================================================
__device__ __forceinline__ void ph0_body(
    int bid,
    const float* __restrict__ E32b, const float* __restrict__ w511f,
    const int* __restrict__ tyv, const float* __restrict__ alphaf,
    unsigned short* __restrict__ Hleaf, float* __restrict__ Cleaf,
    unsigned short* __restrict__ A64,
    unsigned short* __restrict__ Hside, float* __restrict__ Cside,
    int* __restrict__ rowidx, int* __restrict__ cnt) {
    const int t = threadIdx.x;
    if (bid < 64) {
        int o = bid * 256 + t;
        int ty = o >> 9, j = o & 511;
        int Pb = (j >> 4) * 64 + (j & 15);
        const float* Er = E32b + (size_t)ty * 2048;
        float ig = Er[Pb], gg = Er[Pb + 32], og = Er[Pb + 48];
        float cn = sigf(ig) * tanhfast(gg);
        float hn = sigf(og) * tanhfast(cn);
        unsigned short hb = f2bf(hn);
        Hleaf[o] = hb;
        Cleaf[o] = cn;
        A64[ty * 1024 + j] = hb;
        A64[ty * 1024 + 512 + j] = 0;
        A64[(32 + ty) * 1024 + j] = 0;
        A64[(32 + ty) * 1024 + 512 + j] = hb;
    }
    // leaf_int: 16384 rows strided over 512 blocks x 4 waves x 8 rows
    {
        int wave = t >> 6, jc = (t & 63) * 8;
        int r0 = bid * 32 + wave * 8;
        int tys[8];
        #pragma unroll
        for (int i = 0; i < 8; ++i) tys[i] = tyv[16320 + r0 + i];
        #pragma unroll
        for (int i = 0; i < 8; ++i) {
            if (tys[i] > 1) continue;
            int r = r0 + i;
            int gn = 16320 + r;
            float al = alphaf[gn];
            int l = r >> 6, b = r & 63;
            const float* Er = E32b + (size_t)tys[i] * 2048;
            short8 hv;
            float cv[8];
            #pragma unroll
            for (int jj = 0; jj < 8; ++jj) {
                int j = jc + jj;
                int Pb = (j >> 4) * 64 + (j & 15);
                float ig = Er[Pb]      + al * w511f[Pb];
                float gg = Er[Pb + 32] + al * w511f[Pb + 32];
                float og = Er[Pb + 48] + al * w511f[Pb + 48];
                float cn = sigf(ig) * tanhfast(gg);
                float hn = sigf(og) * tanhfast(cn);
                hv[jj] = (short)f2bf(hn);
                cv[jj] = cn;
            }
            *(short8*)(Hside + (size_t)r * 512 + jc) = hv;
            if ((l & 1) == 0) {
                size_t cr = ((size_t)((l >> 1) * 64 + b)) * 512 + jc;
                float4 c0 = {cv[0], cv[1], cv[2], cv[3]};
                float4 c1 = {cv[4], cv[5], cv[6], cv[7]};
                *(float4*)(Cside + cr) = c0;
                *(float4*)(Cside + cr + 4) = c1;
            }
        }
    }
    if (bid >= 64 && bid < 96) {
        int r = (bid - 64) * 256 + t;
        int lf = (r >> 6) * 128 + (r & 63);
        if (tyv[16320 + lf] <= 1 || tyv[16320 + lf + 64] <= 1) {
            int p = atomicAdd(cnt, 1);
            rowidx[p] = r;
        }
    }
}

// ===========================================================================
// Generic small-M table GEMM via MFMA: C[r][P] = sum_k A[r][k]*B[P][k] (+bias).
// KT k-tiles of 64. BIAS: rows 0..31 -> C0, init bias. !BIAS: rows 0..31 ->
// C0, 32..63 -> C1, init 0. A row length = KT*64 bf16. One tile-row, by=col.
// ===========================================================================
template<int KT, bool BIAS>
__device__ __forceinline__ void table_gemm_body(
    char* smemraw, const unsigned short* __restrict__ Abf,
    const unsigned short* __restrict__ Bt, const float* __restrict__ biasP,
    float* __restrict__ C0, float* __restrict__ C1, int by) {
    unsigned short* AB = (unsigned short*)smemraw;
    const int t = threadIdx.x;
    const int w = t >> 6, lane = t & 63;
    const int wr = w >> 1, wc = w & 1;
    const int lane15 = lane & 15, lg = lane >> 4;
    const int bcol0 = by * 128;
    const int lanek8 = (lane & 7) * 8;
    const int ROWS = BIAS ? 32 : 64;

    const unsigned short* aA[4];
    const unsigned short* wB[4];
    #pragma unroll
    for (int q = 0; q < 4; ++q) {
        int m = w * 32 + q * 8 + (lane >> 3);
        int r = (m < ROWS) ? m : (ROWS - 1);
        aA[q] = Abf + (size_t)r * (KT * 64);
        int P = bcol0 + w * 32 + q * 8 + (lane >> 3);
        wB[q] = Bt + (size_t)P * (KT * 64);
    }
    auto stage = [&](int kt, int cur) {
        unsigned short* Ad = AB + cur * 16384;
        unsigned short* Bd = Ad + 8192;
        #pragma unroll
        for (int q = 0; q < 4; ++q) {
            __builtin_amdgcn_global_load_lds(AS1(aA[q] + kt * 64 + lanek8),
                                             AS3(Ad + w * 2048 + q * 512), 16, 0, 0);
            __builtin_amdgcn_global_load_lds(AS1(wB[q] + kt * 64 + lanek8),
                                             AS3(Bd + w * 2048 + q * 512), 16, 0, 0);
        }
    };
    stage(0, 0);
    f32x4 acc[4][4];
    int P4[4];
    #pragma unroll
    for (int q = 0; q < 4; ++q) P4[q] = bcol0 + wc * 64 + q * 16 + lane15;
    #pragma unroll
    for (int mi = 0; mi < 4; ++mi)
        #pragma unroll
        for (int reg = 0; reg < 4; ++reg)
            #pragma unroll
            for (int q = 0; q < 4; ++q)
                acc[mi][q][reg] = BIAS ? biasP[P4[q]] : 0.f;
    int cur = 0;
    for (int kt = 0; kt < KT; ++kt) {
        __syncthreads();
        if (kt < KT - 1) stage(kt + 1, cur ^ 1);
        const unsigned short* Ac = AB + cur * 16384;
        const unsigned short* Bc = Ac + 8192;
        #pragma unroll
        for (int ks = 0; ks < 2; ++ks) {
            short8 av[4], bv[4];
            #pragma unroll
            for (int mi = 0; mi < 4; ++mi)
                av[mi] = *(const short8*)(Ac + (wr * 64 + mi * 16 + lane15) * 64 + ks * 32 + lg * 8);
            #pragma unroll
            for (int q = 0; q < 4; ++q)
                bv[q] = *(const short8*)(Bc + (wc * 64 + q * 16 + lane15) * 64 + ks * 32 + lg * 8);
            #pragma unroll
            for (int mi = 0; mi < 4; ++mi)
                #pragma unroll
                for (int q = 0; q < 4; ++q)
                    acc[mi][q] = __builtin_amdgcn_mfma_f32_16x16x32_bf16(av[mi], bv[q], acc[mi][q], 0, 0, 0);
        }
        cur ^= 1;
    }
    #pragma unroll
    for (int mi = 0; mi < 4; ++mi)
        #pragma unroll
        for (int reg = 0; reg < 4; ++reg) {
            int ro = wr * 64 + mi * 16 + lg * 4 + reg;
            #pragma unroll
            for (int q = 0; q < 4; ++q) {
                float v = acc[mi][q][reg];
                if (ro < 32) C0[(size_t)ro * 2048 + P4[q]] = v;
                else if (!BIAS && ro < 64) C1[(size_t)(ro - 32) * 2048 + P4[q]] = v;
            }
        }
    __syncthreads();
}

// ===========================================================================
// d=7 table path; SKIPS rows with an int-leaf child (handled by compact MFMA,
// disjoint -> same phase safe). smem floats: Es/GLs/GRs[32][129], Cls[32][33],
// w5s[128]  (54,272 B)
// ===========================================================================
__device__ __forceinline__ void d7_table_body(
    char* smemraw,
    const float* __restrict__ E32b, const float* __restrict__ GLt,
    const float* __restrict__ GRt, const float* __restrict__ Cleaf,
    const float* __restrict__ w511f,
    const int* __restrict__ tyv, const float* __restrict__ alphaf,
    unsigned short* __restrict__ out_h, float* __restrict__ out_c,
    int bx, int by) {
    float* Es  = (float*)smemraw;
    float* GLs = Es + 32 * 129;
    float* GRs = GLs + 32 * 129;
    float* Cls = GRs + 32 * 129;
    float* w5s = Cls + 32 * 33;
    const int t = threadIdx.x;
    const int j0 = by * 32;
    const int r = bx * 256 + t;

    for (int i = t; i < 32 * 128; i += 256) {
        int ty = i >> 7, pp = i & 127;
        int gp = ((j0 >> 4) + (pp >> 6)) * 64 + (pp & 63);
        Es[ty * 129 + pp]  = E32b[ty * 2048 + gp];
        GLs[ty * 129 + pp] = GLt[ty * 2048 + gp];
        GRs[ty * 129 + pp] = GRt[ty * 2048 + gp];
    }
    for (int i = t; i < 32 * 32; i += 256) {
        int ty = i >> 5, jl = i & 31;
        Cls[ty * 33 + jl] = Cleaf[ty * 512 + j0 + jl];
    }
    if (t < 128) w5s[t] = w511f[((j0 >> 4) + (t >> 6)) * 64 + (t & 63)];
    __syncthreads();

    int gn = 8128 + r;
    int tyP = tyv[gn];
    float aP = alphaf[gn];
    int lf = (r >> 6) * 128 + (r & 63);
    int tyL = tyv[16320 + lf];
    int tyR = tyv[16320 + lf + 64];
    bool skip = (tyL <= 1) || (tyR <= 1);
    bool evenl = (((r >> 6) & 1) == 0);
    size_t crow = ((size_t)((r >> 7) * 64 + (r & 63))) * 512;

    if (!skip) {
        #pragma unroll
        for (int j8 = 0; j8 < 4; ++j8) {
            short8 hv;
            float cv[8];
            #pragma unroll
            for (int jj = 0; jj < 8; ++jj) {
                int jl = j8 * 8 + jj;
                int ppb = (jl >> 4) * 64 + (jl & 15);
                float ig = Es[tyP * 129 + ppb]      + aP * w5s[ppb]      + GLs[tyL * 129 + ppb]      + GRs[tyR * 129 + ppb];
                float fg = Es[tyP * 129 + ppb + 16] + aP * w5s[ppb + 16] + GLs[tyL * 129 + ppb + 16] + GRs[tyR * 129 + ppb + 16];
                float gg = Es[tyP * 129 + ppb + 32] + aP * w5s[ppb + 32] + GLs[tyL * 129 + ppb + 32] + GRs[tyR * 129 + ppb + 32];
                float og = Es[tyP * 129 + ppb + 48] + aP * w5s[ppb + 48] + GLs[tyL * 129 + ppb + 48] + GRs[tyR * 129 + ppb + 48];
                float cl = Cls[tyL * 33 + jl];
                float cn = sigf(fg) * cl + sigf(ig) * tanhfast(gg);
                float hn = sigf(og) * tanhfast(cn);
                hv[jj] = (short)f2bf(hn);
                cv[jj] = cn;
            }
            *(short8*)(out_h + (size_t)r * 512 + j0 + j8 * 8) = hv;
            if (evenl) {
                float4 c0 = {cv[0], cv[1], cv[2], cv[3]};
                float4 c1 = {cv[4], cv[5], cv[6], cv[7]};
                *(float4*)(out_c + crow + j0 + j8 * 8) = c0;
                *(float4*)(out_c + crow + j0 + j8 * 8 + 4) = c1;
            }
        }
    }
    __syncthreads();
}

// ===========================================================================
// 128x128 MFMA level tile. MODE 0: inner level. MODE 2: d=7 compacted rows
// (rowidx, clamp idx to nc-1; A/c from Hleaf/Hside/Cleaf/Cside).
// Single-barrier double-buffered K-loop, 64 KB smem.
// ===========================================================================
template<int MODE>
__device__ __forceinline__ void mfma_tile(
    char* smemraw,
    const unsigned short* __restrict__ WhT, const float* __restrict__ E32b,
    const float* __restrict__ w511f,
    const int* __restrict__ tyv, const float* __restrict__ alphaf,
    const unsigned short* __restrict__ in_h, const float* __restrict__ in_c,
    const unsigned short* __restrict__ Hleaf, const unsigned short* __restrict__ Hside,
    const float* __restrict__ Cleaf, const float* __restrict__ Cside,
    const int* __restrict__ rowidx, int nc,
    unsigned short* __restrict__ out_h, float* __restrict__ out_c,
    int base, int nloc, int bx, int by) {
    unsigned short* AB = (unsigned short*)smemraw;
    const int t = threadIdx.x;
    const int w = t >> 6, lane = t & 63;
    const int wr = w >> 1, wc = w & 1;
    const int lane15 = lane & 15, lg = lane >> 4;
    const int M = nloc * 64;
    const int brow0 = bx * 128;
    const int bcol0 = by * 128;
    const int lanek8 = (lane & 7) * 8;

    const unsigned short* baseL[4];
    const unsigned short* baseR[4];
    const unsigned short* wB[4];
    #pragma unroll
    for (int q = 0; q < 4; ++q) {
        int m = w * 32 + q * 8 + (lane >> 3);
        int r;
        if (MODE == 2) {
            int idx = brow0 + m; if (idx > nc - 1) idx = nc - 1;
            r = rowidx[idx];
        } else {
            r = brow0 + m; if (r > M - 1) r = M - 1;
        }
        int lf = (r >> 6) * 128 + (r & 63);
        if (MODE == 2) {
            int tyL = tyv[16320 + lf];
            int tyR = tyv[16320 + lf + 64];
            baseL[q] = (tyL <= 1) ? (Hside + (size_t)lf * 512)
                                  : (Hleaf + (size_t)tyL * 512);
            baseR[q] = (tyR <= 1) ? (Hside + (size_t)(lf + 64) * 512)
                                  : (Hleaf + (size_t)tyR * 512);
        } else {
            baseL[q] = in_h + (size_t)lf * 512;
            baseR[q] = baseL[q] + 64 * 512;
        }
        int P = bcol0 + w * 32 + q * 8 + (lane >> 3);
        wB[q] = WhT + (size_t)P * 1024;
    }

    auto stage = [&](int kt, int cur) {
        unsigned short* Ad = AB + cur * 16384;
        unsigned short* Bd = Ad + 8192;
        #pragma unroll
        for (int q = 0; q < 4; ++q) {
            const unsigned short* s = (kt < 8) ? (baseL[q] + kt * 64)
                                               : (baseR[q] + (kt - 8) * 64);
            __builtin_amdgcn_global_load_lds(AS1(s + lanek8),
                                             AS3(Ad + w * 2048 + q * 512), 16, 0, 0);
            __builtin_amdgcn_global_load_lds(AS1(wB[q] + kt * 64 + lanek8),
                                             AS3(Bd + w * 2048 + q * 512), 16, 0, 0);
        }
    };

    stage(0, 0);

    f32x4 acc[4][4];
    float w4[4];
    int P4[4];
    int rr[4][4];
    #pragma unroll
    for (int q = 0; q < 4; ++q) {
        P4[q] = bcol0 + wc * 64 + q * 16 + lane15;
        w4[q] = w511f[P4[q]];
    }
    #pragma unroll
    for (int mi = 0; mi < 4; ++mi) {
        #pragma unroll
        for (int reg = 0; reg < 4; ++reg) {
            int r;
            if (MODE == 2) {
                int idx = brow0 + wr * 64 + mi * 16 + lg * 4 + reg;
                if (idx > nc - 1) idx = nc - 1;
                r = rowidx[idx];
            } else {
                r = brow0 + wr * 64 + mi * 16 + lg * 4 + reg;
                if (r > M - 1) r = M - 1;
            }
            rr[mi][reg] = r;
            int gn = base * 64 + r;
            int ty = tyv[gn];
            float al = alphaf[gn];
            const float* Er = E32b + (size_t)ty * 2048;
            #pragma unroll
            for (int q = 0; q < 4; ++q)
                acc[mi][q][reg] = Er[P4[q]] + al * w4[q];
        }
    }

    int cur = 0;
    for (int kt = 0; kt < 16; ++kt) {
        __syncthreads();
        if (kt < 15) stage(kt + 1, cur ^ 1);
        const unsigned short* Ac = AB + cur * 16384;
        const unsigned short* Bc = Ac + 8192;
        #pragma unroll
        for (int ks = 0; ks < 2; ++ks) {
            short8 av[4], bv[4];
            #pragma unroll
            for (int mi = 0; mi < 4; ++mi)
                av[mi] = *(const short8*)(Ac + (wr * 64 + mi * 16 + lane15) * 64 + ks * 32 + lg * 8);
            #pragma unroll
            for (int q = 0; q < 4; ++q)
                bv[q] = *(const short8*)(Bc + (wc * 64 + q * 16 + lane15) * 64 + ks * 32 + lg * 8);
            #pragma unroll
            for (int mi = 0; mi < 4; ++mi)
                #pragma unroll
                for (int q = 0; q < 4; ++q)
                    acc[mi][q] = __builtin_amdgcn_mfma_f32_16x16x32_bf16(av[mi], bv[q], acc[mi][q], 0, 0, 0);
        }
        cur ^= 1;
    }

    const int j = (by * 2 + wc) * 16 + lane15;
    #pragma unroll
    for (int mi = 0; mi < 4; ++mi) {
        #pragma unroll
        for (int reg = 0; reg < 4; ++reg) {
            int r = rr[mi][reg];
            if (r < M) {
                float ig = acc[mi][0][reg];
                float fg = acc[mi][1][reg];
                float gg = acc[mi][2][reg];
                float og = acc[mi][3][reg];
                float cl;
                if (MODE == 2) {
                    int lf = (r >> 6) * 128 + (r & 63);
                    int tyL = tyv[16320 + lf];
                    cl = (tyL <= 1) ? Cside[(size_t)r * 512 + j]
                                    : Cleaf[(size_t)tyL * 512 + j];
                } else {
                    cl = in_c[(size_t)r * 512 + j];
                }
                float cn = sigf(fg) * cl + sigf(ig) * tanhfast(gg);
                float hn = sigf(og) * tanhfast(cn);
                out_h[(size_t)r * 512 + j] = f2bf(hn);
                if (((r >> 6) & 1) == 0)
                    out_c[((size_t)((r >> 7) * 64 + (r & 63))) * 512 + j] = cn;
            }
        }
    }
}

// ===========================================================================
// head body (smem floats: rh[512] xs[512] part[16*17])
// ===========================================================================
__device__ __forceinline__ void head_body(
    char* smemraw,
    const unsigned short* __restrict__ rootH, const float* __restrict__ W1t,
    const float* __restrict__ b1, const float* __restrict__ W2t,
    const float* __restrict__ b2, const float* __restrict__ vmask,
    float* __restrict__ outp, int b) {
    float* rh = (float*)smemraw;
    float* xs = rh + 512;
    float* part = xs + 512;
    int t = threadIdx.x;
    rh[t] = bf2f(rootH[b * 512 + t]);
    rh[t + 256] = bf2f(rootH[b * 512 + t + 256]);
    __syncthreads();
    #pragma unroll
    for (int jj = 0; jj < 2; ++jj) {
        int jx = t + jj * 256;
        float acc = b1[jx];
        for (int k = 0; k < 512; ++k) acc = fmaf(rh[k], W1t[k * 512 + jx], acc);
        xs[jx] = fmaxf(acc, 0.f);
    }
    __syncthreads();
    int op = t & 15, seg = t >> 4;
    float p = 0.f;
    for (int k = seg * 32; k < seg * 32 + 32; ++k) p = fmaf(xs[k], W2t[k * 16 + op], p);
    part[seg * 17 + op] = p;
    __syncthreads();
    if (t < 16) {
        float s = 0.f;
        #pragma unroll
        for (int g = 0; g < 16; ++g) s += part[g * 17 + t];
        float logit = s + b2[t] + logf(vmask[b * 16 + t]);
        float z = logit * (1.0f / 3.0f);
        float m = z;
        for (int o2 = 8; o2; o2 >>= 1) m = fmaxf(m, __shfl_xor(m, o2, 16));
        float e = __expf(z - m);
        float ssum = e;
        for (int o2 = 8; o2; o2 >>= 1) ssum += __shfl_xor(ssum, o2, 16);
        outp[b * 16 + t] = e / ssum;
    }
}

// ===========================================================================
// Cooperative fused kernel: ph0 (leaf tables/A64/leaf_int/flag) -> GLGR MFMA
// -> d7 (table + compact MFMA, disjoint) -> d6..0 -> head.
// ===========================================================================
__global__ __launch_bounds__(256) void tree_main(
    const unsigned short* WhT, const float* E32b, const float* w511f,
    const int* tyv, const float* alphaf,
    unsigned short* Hleaf, unsigned short* Hside,
    float* Cleaf, float* Cside, unsigned short* A64,
    float* GLt, float* GRt, int* rowidx, int* cnt,
    unsigned short* Xh, float* Xc, unsigned short* Yh, float* Yc,
    const float* W1t, const float* b1, const float* W2t, const float* b2,
    const float* vmask, float* outp) {
    cg::grid_group grid = cg::this_grid();
    extern __shared__ char smem[];
    const int bid = blockIdx.x;

    // ph0
    ph0_body(bid, E32b, w511f, tyv, alphaf, Hleaf, Cleaf, A64, Hside, Cside,
             rowidx, cnt);
    __threadfence(); grid.sync();

    // ph1: GLGR via MFMA (16 tiles)
    if (bid < 16)
        table_gemm_body<16, false>(smem, A64, WhT, nullptr, GLt, GRt, bid);
    __threadfence(); grid.sync();

    // ph2: d=7 table (skips flagged rows) + compacted MFMA (flagged rows)
    d7_table_body(smem, E32b, GLt, GRt, Cleaf, w511f, tyv, alphaf,
                  Xh, Xc, bid & 31, bid >> 5);
    {
        int nc = *cnt;
        int rb = ((nc + 127) & ~127) >> 7;
        for (int T = bid; T < rb * 16; T += 512)
            mfma_tile<2>(smem, WhT, E32b, w511f, tyv, alphaf, nullptr, nullptr,
                         Hleaf, Hside, Cleaf, Cside, rowidx, nc,
                         Xh, Xc, 127, 128, T % rb, T / rb);
    }
    __threadfence(); grid.sync();

    // ph3..9: levels d=6..0
    for (int d = 6; d >= 0; --d) {
        int nloc = 1 << d;
        int gx = (nloc >= 2) ? (nloc >> 1) : 1;
        unsigned short* oh = (d & 1) ? Xh : Yh;
        float* oc          = (d & 1) ? Xc : Yc;
        const unsigned short* ih = (d & 1) ? Yh : Xh;
        const float* ic          = (d & 1) ? Yc : Xc;
        int ntiles = gx * 16;
        if (bid < ntiles)
            mfma_tile<0>(smem, WhT, E32b, w511f, tyv, alphaf, ih, ic,
                         nullptr, nullptr, nullptr, nullptr, nullptr, 0,
                         oh, oc, nloc - 1, nloc, bid % gx, bid / gx);
        __threadfence(); grid.sync();
    }

    // head (root h in Yh)
    if (bid < 64)
        head_body(smem, Yh, W1t, b1, W2t, b2, vmask, outp, bid);
}

// ===========================================================================
// Fallback wrappers (non-cooperative path)
// ===========================================================================
__global__ __launch_bounds__(256) void ph0_k(
    const float* __restrict__ E32b, const float* __restrict__ w511f,
    const int* __restrict__ tyv, const float* __restrict__ alphaf,
    unsigned short* __restrict__ Hleaf, float* __restrict__ Cleaf,
    unsigned short* __restrict__ A64,
    unsigned short* __restrict__ Hside, float* __restrict__ Cside,
    int* __restrict__ rowidx, int* __restrict__ cnt) {
    ph0_body(blockIdx.x, E32b, w511f, tyv, alphaf, Hleaf, Cleaf, A64,
             Hside, Cside, rowidx, cnt);
}

__global__ __launch_bounds__(256) void glgr_k(
    const unsigned short* __restrict__ A64, const unsigned short* __restrict__ WhT,
    float* __restrict__ GLt, float* __restrict__ GRt) {
    extern __shared__ char smem[];
    table_gemm_body<16, false>(smem, A64, WhT, nullptr, GLt, GRt, blockIdx.x);
}

__global__ __launch_bounds__(256) void d7t_k(
    const float* __restrict__ E32b, const float* __restrict__ GLt,
    const float* __restrict__ GRt, const float* __restrict__ Cleaf,
    const float* __restrict__ w511f,
    const int* __restrict__ tyv, const float* __restrict__ alphaf,
    unsigned short* __restrict__ out_h, float* __restrict__ out_c) {
    extern __shared__ char smem[];
    d7_table_body(smem, E32b, GLt, GRt, Cleaf, w511f, tyv, alphaf,
                  out_h, out_c, blockIdx.x, blockIdx.y);
}

__global__ __launch_bounds__(256) void d7c_k(
    const unsigned short* __restrict__ WhT, const float* __restrict__ E32b,
    const float* __restrict__ w511f,
    const int* __restrict__ tyv, const float* __restrict__ alphaf,
    const unsigned short* __restrict__ Hleaf, const unsigned short* __restrict__ Hside,
    const float* __restrict__ Cleaf, const float* __restrict__ Cside,
    const int* __restrict__ rowidx, const int* __restrict__ cnt,
    unsigned short* __restrict__ out_h, float* __restrict__ out_c) {
    extern __shared__ char smem[];
    int nc = *cnt;
    int padded = (nc + 127) & ~127;
    if ((int)blockIdx.x * 128 >= padded) return;
    mfma_tile<2>(smem, WhT, E32b, w511f, tyv, alphaf, nullptr, nullptr,
                 Hleaf, Hside, Cleaf, Cside, rowidx, nc,
                 out_h, out_c, 127, 128, blockIdx.x, blockIdx.y);
}

__global__ __launch_bounds__(256) void lvl_k(
    const unsigned short* __restrict__ WhT, const float* __restrict__ E32b,
    const float* __restrict__ w511f,
    const int* __restrict__ tyv, const float* __restrict__ alphaf,
    const unsigned short* __restrict__ in_h, const float* __restrict__ in_c,
    unsigned short* __restrict__ out_h, float* __restrict__ out_c,
    int base, int nloc) {
    extern __shared__ char smem[];
    mfma_tile<0>(smem, WhT, E32b, w511f, tyv, alphaf, in_h, in_c,
                 nullptr, nullptr, nullptr, nullptr, nullptr, 0,
                 out_h, out_c, base, nloc, blockIdx.x, blockIdx.y);
}

__global__ __launch_bounds__(256) void head_k(
    const unsigned short* __restrict__ rootH, const float* __restrict__ W1t,
    const float* __restrict__ b1, const float* __restrict__ W2t,
    const float* __restrict__ b2, const float* __restrict__ vmask,
    float* __restrict__ outp) {
    extern __shared__ char smem[];
    head_body(smem, rootH, W1t, b1, W2t, b2, vmask, outp, blockIdx.x);
}

extern "C" void kernel_launch(void* const* d_in, const int* in_sizes, int n_in,
                              void* d_out, int out_size, void* d_ws, size_t ws_size,
                              hipStream_t stream) {
    const int*   node_types = (const int*)d_in[0];
    const float* node_args  = (const float*)d_in[1];
    const float* vmask      = (const float*)d_in[2];
    const float* emb_table  = (const float*)d_in[3];
    const float* W_ih       = (const float*)d_in[4];
    const float* W_hh       = (const float*)d_in[5];
    const float* b_ih       = (const float*)d_in[6];
    const float* b_hh       = (const float*)d_in[7];
    const float* W1         = (const float*)d_in[8];
    const float* b1         = (const float*)d_in[9];
    const float* W2         = (const float*)d_in[10];
    const float* b2         = (const float*)d_in[11];
    float* out = (float*)d_out;

    char* ws = (char*)d_ws;
    size_t off = 0;
    auto alloc = [&](size_t bytes) { char* p = ws + off; off += (bytes + 255) & ~(size_t)255; return p; };
    unsigned short* WhT  = (unsigned short*)alloc((size_t)2048 * 1024 * 2);
    float* E32b          = (float*)alloc((size_t)32 * 2048 * 4);
    float* w511f         = (float*)alloc(2048 * 4);
    float* W1t           = (float*)alloc((size_t)512 * 512 * 4);
    float* W2t           = (float*)alloc(8192 * 4);
    int*   tyv           = (int*)alloc(32704 * 4);
    float* alphaf        = (float*)alloc(32704 * 4);
    unsigned short* Hleaf= (unsigned short*)alloc((size_t)32 * 512 * 2);
    float* Cleaf         = (float*)alloc((size_t)32 * 512 * 4);
    unsigned short* A64  = (unsigned short*)alloc((size_t)64 * 1024 * 2);
    float* GLt           = (float*)alloc((size_t)32 * 2048 * 4);
    float* GRt           = (float*)alloc((size_t)32 * 2048 * 4);
    int*   rowidx        = (int*)alloc(8448 * 4);
    int*   cnt           = (int*)alloc(256);
    unsigned short* Hside= (unsigned short*)alloc((size_t)16384 * 512 * 2);
    float* Cside         = (float*)alloc((size_t)8192 * 512 * 4);
    unsigned short* Xh   = (unsigned short*)alloc((size_t)8192 * 512 * 2);
    unsigned short* Yh   = (unsigned short*)alloc((size_t)4096 * 512 * 2);
    float* Xc            = (float*)alloc((size_t)4096 * 512 * 4);
    float* Yc            = (float*)alloc((size_t)2048 * 512 * 4);

    if (ws_size < off) {
        zero_out<<<(out_size + 255) / 256, 256, 0, stream>>>(out, out_size);
        return;
    }

    prep_all<<<1505, 256, 0, stream>>>(W_hh, WhT, W1, W1t, node_types, node_args,
                                       emb_table, W2, W2t, tyv, alphaf,
                                       W_ih, b_ih, b_hh, E32b, w511f, rowidx, cnt);

    bool coop_ok = false;
    {
        int occ = 0;
        hipError_t qe = hipOccupancyMaxActiveBlocksPerMultiprocessor(
            &occ, tree_main, 256, 65536);
        if (qe == hipSuccess && occ >= 2) coop_ok = true;
    }
    if (coop_ok) {
        const unsigned short* cWhT = WhT;  const float* cE32b = E32b;
        const float* cw511 = w511f;        const int* ctyv = tyv;
        const float* calpha = alphaf;      const float* cW1t = W1t;
        const float* cW2t = W2t;
        void* kargs[] = {
            (void*)&cWhT, (void*)&cE32b, (void*)&cw511, (void*)&ctyv, (void*)&calpha,
            (void*)&Hleaf, (void*)&Hside, (void*)&Cleaf, (void*)&Cside, (void*)&A64,
            (void*)&GLt, (void*)&GRt, (void*)&rowidx, (void*)&cnt,
            (void*)&Xh, (void*)&Xc, (void*)&Yh, (void*)&Yc,
            (void*)&cW1t, (void*)&b1, (void*)&cW2t, (void*)&b2,
            (void*)&vmask, (void*)&out };
        hipError_t le = hipLaunchCooperativeKernel(
            tree_main, dim3(512), dim3(256), kargs, (unsigned)65536, stream);
        if (le != hipSuccess) coop_ok = false;
    }
    if (!coop_ok) {
        ph0_k<<<512, 256, 0, stream>>>(E32b, w511f, tyv, alphaf, Hleaf, Cleaf,
                                       A64, Hside, Cside, rowidx, cnt);
        glgr_k<<<16, 256, 65536, stream>>>(A64, WhT, GLt, GRt);
        d7t_k<<<dim3(32, 16), 256, 54272, stream>>>(
            E32b, GLt, GRt, Cleaf, w511f, tyv, alphaf, Xh, Xc);
        d7c_k<<<dim3(64, 16), 256, 65536, stream>>>(
            WhT, E32b, w511f, tyv, alphaf, Hleaf, Hside, Cleaf, Cside,
            rowidx, cnt, Xh, Xc);
        for (int d = 6; d >= 0; --d) {
            int nloc = 1 << d;
            unsigned short* oh = (d & 1) ? Xh : Yh;
            float* oc          = (d & 1) ? Xc : Yc;
            const unsigned short* ih = (d & 1) ? Yh : Xh;
            const float* ic          = (d & 1) ? Yc : Xc;
            int gx = (nloc >= 2) ? (nloc / 2) : 1;
            lvl_k<<<dim3(gx, 16), 256, 65536, stream>>>(
                WhT, E32b, w511f, tyv, alphaf, ih, ic, oh, oc, nloc - 1, nloc);
        }
        head_k<<<64, 256, 5184, stream>>>(Yh, W1t, b1, W2t, b2, vmask, out);
    }
}